// Round 12
// baseline (726.120 us; speedup 1.0000x reference)
//
#include <hip/hip_runtime.h>

// GraphSAGE on MI355X — fp32 I/O, split-bf16 MFMA GEMMs, fused aggregate+GEMM.
// Stages: detect edge dtype -> CSR build (count / 3-kernel scan / fill+nt-store)
//         -> 3x fused(aggregate->LDS->dual GEMM) with decoder fused into layer 3.
// R11: fused grid 512 -> NTILES (3125) — occupancy was the regression cause (20% -> ~50%).

#define N_NODES 50000
#define N_EDGES 800000
#define D 128
#define NB ((N_NODES + 255) / 256)   // 196 scan blocks
#define NTILES (N_NODES / 16)        // 3125 row tiles

typedef __bf16 bf16x8 __attribute__((ext_vector_type(8)));
typedef float f32x4 __attribute__((ext_vector_type(4)));

struct bf16pair { bf16x8 hi, lo; };

__device__ inline bf16pair split8v(f32x4 a, f32x4 b) {
    bf16pair r;
#pragma unroll
    for (int i = 0; i < 4; ++i) {
        float v = a[i];
        __bf16 h = (__bf16)v;
        r.hi[i] = h;
        r.lo[i] = (__bf16)(v - (float)h);
    }
#pragma unroll
    for (int i = 0; i < 4; ++i) {
        float v = b[i];
        __bf16 h = (__bf16)v;
        r.hi[4 + i] = h;
        r.lo[4 + i] = (__bf16)(v - (float)h);
    }
    return r;
}

__device__ inline bf16pair split8(const float* __restrict__ p) {
    return split8v(*reinterpret_cast<const f32x4*>(p),
                   *reinterpret_cast<const f32x4*>(p + 4));
}

// ---------- edge dtype detect: int64 edge values < 2^31 have zero high words ----------
__global__ void detect_kernel(const int* __restrict__ ew, int* __restrict__ flag) {
    __shared__ int s;
    if (threadIdx.x == 0) s = 0;
    __syncthreads();
    int v = 0;
    for (int i = threadIdx.x; i < 1024; i += 256) v |= ew[2 * i + 1];
    if (v) atomicOr(&s, 1);
    __syncthreads();
    if (threadIdx.x == 0) flag[0] = s ? 1 : 2;   // words per element
}

// ---------- CSR build ----------
__global__ void count_kernel(const int* __restrict__ ew, const int* __restrict__ flag,
                             int* __restrict__ cnt) {
    int st = flag[0];
    int e = blockIdx.x * blockDim.x + threadIdx.x;
    if (e < N_EDGES) {
        int d = ew[(size_t)st * (N_EDGES + e)];
        atomicAdd(&cnt[d], 1);
    }
}

// scan1: per-block (256 entries) exclusive prefix into off, block sums into bsum
__global__ __launch_bounds__(256) void scan1_kernel(const int* __restrict__ cnt,
                                                    int* __restrict__ off,
                                                    int* __restrict__ bsum) {
    const int tid = threadIdx.x, lane = tid & 63, wid = tid >> 6;
    const int i = blockIdx.x * 256 + tid;
    int orig = (i < N_NODES) ? cnt[i] : 0;
    int v = orig;
#pragma unroll
    for (int d = 1; d < 64; d <<= 1) {
        int t = __shfl_up(v, d, 64);
        if (lane >= d) v += t;
    }
    __shared__ int ws[4];
    if (lane == 63) ws[wid] = v;
    __syncthreads();
    int base = 0;
    for (int w = 0; w < wid; ++w) base += ws[w];
    v += base;                            // inclusive in-block prefix
    if (i < N_NODES) off[i] = v - orig;   // exclusive (block-local)
    if (tid == 255) bsum[blockIdx.x] = v; // block total
}

// scan2: single block scans NB block sums -> exclusive bases; writes off[N]=total
__global__ __launch_bounds__(256) void scan2_kernel(const int* __restrict__ bsum,
                                                    int* __restrict__ bbase,
                                                    int* __restrict__ off) {
    const int tid = threadIdx.x, lane = tid & 63, wid = tid >> 6;
    int orig = (tid < NB) ? bsum[tid] : 0;
    int v = orig;
#pragma unroll
    for (int d = 1; d < 64; d <<= 1) {
        int t = __shfl_up(v, d, 64);
        if (lane >= d) v += t;
    }
    __shared__ int ws[4];
    if (lane == 63) ws[wid] = v;
    __syncthreads();
    int base = 0;
    for (int w = 0; w < wid; ++w) base += ws[w];
    v += base;
    if (tid < NB) bbase[tid] = v - orig;   // exclusive block base
    if (tid == NB - 1) off[N_NODES] = v;   // total == N_EDGES
}

// scan3: add block base, fill cursor
__global__ __launch_bounds__(256) void scan3_kernel(int* __restrict__ off,
                                                    const int* __restrict__ bbase,
                                                    int* __restrict__ cursor) {
    int i = blockIdx.x * 256 + threadIdx.x;
    if (i < N_NODES) {
        int v = off[i] + bbase[blockIdx.x];
        off[i] = v;
        cursor[i] = v;
    }
}

__global__ void fill_kernel(const int* __restrict__ ew, const int* __restrict__ flag,
                            int* __restrict__ cursor, int* __restrict__ csr) {
    int st = flag[0];
    int e = blockIdx.x * blockDim.x + threadIdx.x;
    if (e < N_EDGES) {
        int d = ew[(size_t)st * (N_EDGES + e)];
        int sidx = ew[(size_t)st * e];
        int pos = atomicAdd(&cursor[d], 1);
        __builtin_nontemporal_store(sidx, &csr[pos]);
    }
}

// ---------- fused: segment-mean aggregate (16-node tile -> LDS) + dual GEMM ----------
// out = mean_aggr(hin) @ W1^T + hin @ W2^T + b (optional relu).
// If dec != nullptr: also dec[i][0..1] = out_row_i @ Wo^T + bo (decoder fused, layer 3).
// MFMA 16x16x32 bf16 fragment maps: A row=lane&15, k=8*(lane>>4)+i; B col=lane&15 same k;
// D col=lane&15, row=4*(lane>>4)+r (m89-verified). fp32 accuracy via split hi/lo bf16.
// LDS agg tile uses 8-float-unit rotation (unit+row)&15 to break the D=128 bank conflict.
// Grid = NTILES: one tile per block (occupancy ~50% at VGPR=120; latency-bound gather
// needs resident waves, not traffic reduction — R10 counters).
__global__ __launch_bounds__(256) void fused_kernel(const float* __restrict__ hin,
                                                    const int* __restrict__ off,
                                                    const int* __restrict__ csr,
                                                    const float* __restrict__ W1,
                                                    const float* __restrict__ W2,
                                                    const float* __restrict__ bias,
                                                    float* __restrict__ hout,
                                                    int do_relu,
                                                    const float* __restrict__ Wo,
                                                    const float* __restrict__ bo,
                                                    float* __restrict__ dec) {
    __shared__ float sAgg[16 * 128];
    __shared__ float part[4][16][2];
    const int lane = threadIdx.x & 63;
    const int wid = threadIdx.x >> 6;     // 4 waves: col ranges of 32
    const int colbase = wid * 32;
    const int lr = lane & 15;
    const int lg = lane >> 4;

    // W fragments resident in registers for the whole kernel
    bf16pair B1[2][4], B2[2][4];
    for (int ct = 0; ct < 2; ++ct) {
        int j = colbase + ct * 16 + lr;
        for (int kk = 0; kk < 4; ++kk) {
            int k = kk * 32 + lg * 8;
            B1[ct][kk] = split8(W1 + j * D + k);
            B2[ct][kk] = split8(W2 + j * D + k);
        }
    }
    float bb0 = bias[colbase + lr];
    float bb1 = bias[colbase + 16 + lr];
    const int decode = (dec != nullptr);
    float wo00 = 0.f, wo01 = 0.f, wo10 = 0.f, wo11 = 0.f, bo0 = 0.f, bo1 = 0.f;
    if (decode) {
        wo00 = Wo[colbase + lr];       wo01 = Wo[colbase + 16 + lr];
        wo10 = Wo[D + colbase + lr];   wo11 = Wo[D + colbase + 16 + lr];
        bo0 = bo[0];                   bo1 = bo[1];
    }

    for (int rt = blockIdx.x; rt < NTILES; rt += gridDim.x) {
        __syncthreads();   // S1: sAgg/part free from previous iteration's readers
        // ---- phase 1: each wave aggregates 4 of the tile's 16 rows ----
        for (int rr = 0; rr < 4; ++rr) {
            int row = wid * 4 + rr;
            int node = rt * 16 + row;
            int beg = off[node], end = off[node + 1];
            float ax = 0.f, ay = 0.f;
            int j = beg;
            for (; j + 7 < end; j += 8) {
                int s0 = csr[j],     s1 = csr[j + 1], s2 = csr[j + 2], s3 = csr[j + 3];
                int s4 = csr[j + 4], s5 = csr[j + 5], s6 = csr[j + 6], s7 = csr[j + 7];
                float2 v0 = *reinterpret_cast<const float2*>(hin + (size_t)s0 * D + lane * 2);
                float2 v1 = *reinterpret_cast<const float2*>(hin + (size_t)s1 * D + lane * 2);
                float2 v2 = *reinterpret_cast<const float2*>(hin + (size_t)s2 * D + lane * 2);
                float2 v3 = *reinterpret_cast<const float2*>(hin + (size_t)s3 * D + lane * 2);
                float2 v4 = *reinterpret_cast<const float2*>(hin + (size_t)s4 * D + lane * 2);
                float2 v5 = *reinterpret_cast<const float2*>(hin + (size_t)s5 * D + lane * 2);
                float2 v6 = *reinterpret_cast<const float2*>(hin + (size_t)s6 * D + lane * 2);
                float2 v7 = *reinterpret_cast<const float2*>(hin + (size_t)s7 * D + lane * 2);
                ax += (v0.x + v1.x) + (v2.x + v3.x) + (v4.x + v5.x) + (v6.x + v7.x);
                ay += (v0.y + v1.y) + (v2.y + v3.y) + (v4.y + v5.y) + (v6.y + v7.y);
            }
            for (; j < end; ++j) {
                int s = csr[j];
                float2 v = *reinterpret_cast<const float2*>(hin + (size_t)s * D + lane * 2);
                ax += v.x;
                ay += v.y;
            }
            int c = end - beg;
            if (c < 1) c = 1;
            float fc = (float)c;
            // swizzled LDS store: col = lane*2 lives in 8-float unit (lane>>2), rotated by row
            int unit = ((lane >> 2) + row) & 15;
            int phys = row * 128 + unit * 8 + (lane & 3) * 2;
            sAgg[phys] = ax / fc;
            sAgg[phys + 1] = ay / fc;
        }
        __syncthreads();   // S2: agg tile ready
        // ---- phase 2: dual GEMM on this 16-row tile ----
        bf16pair Af1[4], Af2[4];
        for (int kk = 0; kk < 4; ++kk) {
            int k = kk * 32 + lg * 8;
            int unit = ((k >> 3) + lr) & 15;
            const float* ap = &sAgg[lr * 128 + unit * 8];
            Af1[kk] = split8v(*reinterpret_cast<const f32x4*>(ap),
                              *reinterpret_cast<const f32x4*>(ap + 4));
            Af2[kk] = split8(hin + (size_t)(rt * 16 + lr) * D + k);
        }
        float p0[4] = {0.f, 0.f, 0.f, 0.f}, p1[4] = {0.f, 0.f, 0.f, 0.f};
        for (int ct = 0; ct < 2; ++ct) {
            float bb = ct ? bb1 : bb0;
            f32x4 acc = {bb, bb, bb, bb};
            for (int kk = 0; kk < 4; ++kk) {
                acc = __builtin_amdgcn_mfma_f32_16x16x32_bf16(Af1[kk].hi, B1[ct][kk].hi, acc, 0, 0, 0);
                acc = __builtin_amdgcn_mfma_f32_16x16x32_bf16(Af1[kk].lo, B1[ct][kk].hi, acc, 0, 0, 0);
                acc = __builtin_amdgcn_mfma_f32_16x16x32_bf16(Af1[kk].hi, B1[ct][kk].lo, acc, 0, 0, 0);
                acc = __builtin_amdgcn_mfma_f32_16x16x32_bf16(Af2[kk].hi, B2[ct][kk].hi, acc, 0, 0, 0);
                acc = __builtin_amdgcn_mfma_f32_16x16x32_bf16(Af2[kk].lo, B2[ct][kk].hi, acc, 0, 0, 0);
                acc = __builtin_amdgcn_mfma_f32_16x16x32_bf16(Af2[kk].hi, B2[ct][kk].lo, acc, 0, 0, 0);
            }
            float woa = ct ? wo01 : wo00;
            float wob = ct ? wo11 : wo10;
            int col = colbase + ct * 16 + lr;
            for (int r = 0; r < 4; ++r) {
                float v = acc[r];
                if (do_relu) v = fmaxf(v, 0.0f);
                int orow = rt * 16 + lg * 4 + r;
                hout[(size_t)orow * D + col] = v;
                p0[r] += v * woa;
                p1[r] += v * wob;
            }
        }
        if (decode) {
            // reduce partial decoder dots across the 16 lanes (lr) of each row group
#pragma unroll
            for (int m = 1; m < 16; m <<= 1) {
#pragma unroll
                for (int r = 0; r < 4; ++r) {
                    p0[r] += __shfl_xor(p0[r], m, 64);
                    p1[r] += __shfl_xor(p1[r], m, 64);
                }
            }
            if (lr == 0) {
#pragma unroll
                for (int r = 0; r < 4; ++r) {
                    part[wid][lg * 4 + r][0] = p0[r];
                    part[wid][lg * 4 + r][1] = p1[r];
                }
            }
            __syncthreads();   // S3: partials ready
            if (wid == 0 && lane < 16) {
                float s0 = part[0][lane][0] + part[1][lane][0] + part[2][lane][0] + part[3][lane][0] + bo0;
                float s1 = part[0][lane][1] + part[1][lane][1] + part[2][lane][1] + part[3][lane][1] + bo1;
                float2 o;
                o.x = s0;
                o.y = s1;
                *reinterpret_cast<float2*>(dec + (size_t)(rt * 16 + lane) * 2) = o;
            }
        }
    }
}

extern "C" void kernel_launch(void* const* d_in, const int* in_sizes, int n_in,
                              void* d_out, int out_size, void* d_ws, size_t ws_size,
                              hipStream_t stream) {
    const float* x   = (const float*)d_in[0];
    const int* ew    = (const int*)d_in[1];
    const float* Wl1 = (const float*)d_in[2];
    const float* Wr1 = (const float*)d_in[3];
    const float* b1  = (const float*)d_in[4];
    const float* Wl2 = (const float*)d_in[5];
    const float* Wr2 = (const float*)d_in[6];
    const float* b2  = (const float*)d_in[7];
    const float* Wl3 = (const float*)d_in[8];
    const float* Wr3 = (const float*)d_in[9];
    const float* b3  = (const float*)d_in[10];
    const float* Wo  = (const float*)d_in[11];
    const float* bo  = (const float*)d_in[12];

    char* ws = (char*)d_ws;
    size_t o = 0;
    auto alloc = [&](size_t bytes) {
        char* p = ws + o;
        o += (bytes + 255) & ~(size_t)255;
        return p;
    };
    int* flag   = (int*)alloc(4);
    int* cnt    = (int*)alloc((size_t)N_NODES * 4);
    int* off    = (int*)alloc((size_t)(N_NODES + 1) * 4);
    int* cursor = (int*)alloc((size_t)N_NODES * 4);
    int* csr    = (int*)alloc((size_t)N_EDGES * 4);
    int* bsum   = (int*)alloc((size_t)NB * 4);
    int* bbase  = (int*)alloc((size_t)NB * 4);
    float* h1   = (float*)alloc((size_t)N_NODES * D * 4);
    float* h2   = (float*)alloc((size_t)N_NODES * D * 4);

    float* outp = (float*)d_out;                 // [N,2]
    float* h3   = outp + (size_t)N_NODES * 2;    // [N,128], tail of d_out

    hipMemsetAsync(cnt, 0, (size_t)N_NODES * 4, stream);
    detect_kernel<<<1, 256, 0, stream>>>(ew, flag);
    count_kernel<<<(N_EDGES + 255) / 256, 256, 0, stream>>>(ew, flag, cnt);
    scan1_kernel<<<NB, 256, 0, stream>>>(cnt, off, bsum);
    scan2_kernel<<<1, 256, 0, stream>>>(bsum, bbase, off);
    scan3_kernel<<<NB, 256, 0, stream>>>(off, bbase, cursor);
    fill_kernel<<<(N_EDGES + 255) / 256, 256, 0, stream>>>(ew, flag, cursor, csr);

    fused_kernel<<<NTILES, 256, 0, stream>>>(x, off, csr, Wl1, Wr1, b1, h1, 1,
                                             nullptr, nullptr, nullptr);
    fused_kernel<<<NTILES, 256, 0, stream>>>(h1, off, csr, Wl2, Wr2, b2, h2, 1,
                                             nullptr, nullptr, nullptr);
    fused_kernel<<<NTILES, 256, 0, stream>>>(h2, off, csr, Wl3, Wr3, b3, h3, 0,
                                             Wo, bo, outp);
}

// Round 13
// 431.842 us; speedup vs baseline: 1.6814x; 1.6814x over previous
//
#include <hip/hip_runtime.h>

// GraphSAGE on MI355X — split aggregate/GEMM structure (R4) + bf16 gather shadow,
// decoder fused into layer-3 GEMM, hierarchical scan, nt-store fill.
// R13: fused agg+gemm REVERTED (R10/R12: grid-shape conflict; gather needs 50k waves,
// GEMM needs amortized weight fragments — split wins).

#define N_NODES 50000
#define N_EDGES 800000
#define D 128
#define NB ((N_NODES + 255) / 256)   // 196 scan blocks
#define NTILES (N_NODES / 16)        // 3125 row tiles

typedef __bf16 bf16x8 __attribute__((ext_vector_type(8)));
typedef float f32x4 __attribute__((ext_vector_type(4)));
typedef unsigned short u16x8 __attribute__((ext_vector_type(8)));

struct bf16pair { bf16x8 hi, lo; };

__device__ inline unsigned short f2bf(float f) {
    unsigned int u = __float_as_uint(f);
    unsigned int r = u + 0x7fffu + ((u >> 16) & 1u);   // RNE
    return (unsigned short)(r >> 16);
}

__device__ inline bf16pair split8(const float* __restrict__ p) {
    f32x4 a = *reinterpret_cast<const f32x4*>(p);
    f32x4 b = *reinterpret_cast<const f32x4*>(p + 4);
    bf16pair r;
#pragma unroll
    for (int i = 0; i < 4; ++i) {
        float v = a[i];
        __bf16 h = (__bf16)v;
        r.hi[i] = h;
        r.lo[i] = (__bf16)(v - (float)h);
    }
#pragma unroll
    for (int i = 0; i < 4; ++i) {
        float v = b[i];
        __bf16 h = (__bf16)v;
        r.hi[4 + i] = h;
        r.lo[4 + i] = (__bf16)(v - (float)h);
    }
    return r;
}

// ---------- edge dtype detect ----------
__global__ void detect_kernel(const int* __restrict__ ew, int* __restrict__ flag) {
    __shared__ int s;
    if (threadIdx.x == 0) s = 0;
    __syncthreads();
    int v = 0;
    for (int i = threadIdx.x; i < 1024; i += 256) v |= ew[2 * i + 1];
    if (v) atomicOr(&s, 1);
    __syncthreads();
    if (threadIdx.x == 0) flag[0] = s ? 1 : 2;   // words per element
}

// ---------- CSR build ----------
__global__ void count_kernel(const int* __restrict__ ew, const int* __restrict__ flag,
                             int* __restrict__ cnt) {
    int st = flag[0];
    int e = blockIdx.x * blockDim.x + threadIdx.x;
    if (e < N_EDGES) {
        int d = ew[(size_t)st * (N_EDGES + e)];
        atomicAdd(&cnt[d], 1);
    }
}

__global__ __launch_bounds__(256) void scan1_kernel(const int* __restrict__ cnt,
                                                    int* __restrict__ off,
                                                    int* __restrict__ bsum) {
    const int tid = threadIdx.x, lane = tid & 63, wid = tid >> 6;
    const int i = blockIdx.x * 256 + tid;
    int orig = (i < N_NODES) ? cnt[i] : 0;
    int v = orig;
#pragma unroll
    for (int d = 1; d < 64; d <<= 1) {
        int t = __shfl_up(v, d, 64);
        if (lane >= d) v += t;
    }
    __shared__ int ws[4];
    if (lane == 63) ws[wid] = v;
    __syncthreads();
    int base = 0;
    for (int w = 0; w < wid; ++w) base += ws[w];
    v += base;
    if (i < N_NODES) off[i] = v - orig;
    if (tid == 255) bsum[blockIdx.x] = v;
}

__global__ __launch_bounds__(256) void scan2_kernel(const int* __restrict__ bsum,
                                                    int* __restrict__ bbase,
                                                    int* __restrict__ off) {
    const int tid = threadIdx.x, lane = tid & 63, wid = tid >> 6;
    int orig = (tid < NB) ? bsum[tid] : 0;
    int v = orig;
#pragma unroll
    for (int d = 1; d < 64; d <<= 1) {
        int t = __shfl_up(v, d, 64);
        if (lane >= d) v += t;
    }
    __shared__ int ws[4];
    if (lane == 63) ws[wid] = v;
    __syncthreads();
    int base = 0;
    for (int w = 0; w < wid; ++w) base += ws[w];
    v += base;
    if (tid < NB) bbase[tid] = v - orig;
    if (tid == NB - 1) off[N_NODES] = v;
}

__global__ __launch_bounds__(256) void scan3_kernel(int* __restrict__ off,
                                                    const int* __restrict__ bbase,
                                                    int* __restrict__ cursor) {
    int i = blockIdx.x * 256 + threadIdx.x;
    if (i < N_NODES) {
        int v = off[i] + bbase[blockIdx.x];
        off[i] = v;
        cursor[i] = v;
    }
}

__global__ void fill_kernel(const int* __restrict__ ew, const int* __restrict__ flag,
                            int* __restrict__ cursor, int* __restrict__ csr) {
    int st = flag[0];
    int e = blockIdx.x * blockDim.x + threadIdx.x;
    if (e < N_EDGES) {
        int d = ew[(size_t)st * (N_EDGES + e)];
        int sidx = ew[(size_t)st * e];
        int pos = atomicAdd(&cursor[d], 1);
        __builtin_nontemporal_store(sidx, &csr[pos]);
    }
}

// ---------- fp32 -> bf16 shadow convert (for x; h1/h2 shadows come from gemm epilogue) ----------
__global__ __launch_bounds__(256) void tobf16_kernel(const float* __restrict__ in,
                                                     unsigned short* __restrict__ out) {
    int i = blockIdx.x * 256 + threadIdx.x;   // 800000 threads x 8 elts = 6.4M
    const float* p = in + (size_t)i * 8;
    f32x4 a = *reinterpret_cast<const f32x4*>(p);
    f32x4 b = *reinterpret_cast<const f32x4*>(p + 4);
    u16x8 r;
#pragma unroll
    for (int k = 0; k < 4; ++k) r[k] = f2bf(a[k]);
#pragma unroll
    for (int k = 0; k < 4; ++k) r[4 + k] = f2bf(b[k]);
    *reinterpret_cast<u16x8*>(out + (size_t)i * 8) = r;
}

// ---------- segment-mean aggregation, bf16 gather: one wave per node ----------
__global__ __launch_bounds__(256) void aggregate_bf16_kernel(const unsigned short* __restrict__ hb,
                                                             const int* __restrict__ off,
                                                             const int* __restrict__ csr,
                                                             float* __restrict__ agg) {
    int gw = blockIdx.x * 4 + (threadIdx.x >> 6);
    int lane = threadIdx.x & 63;
    if (gw >= N_NODES) return;
    int beg = off[gw], end = off[gw + 1];
    float ax = 0.f, ay = 0.f;
    int j = beg;
    for (; j + 7 < end; j += 8) {
        unsigned int u0 = *reinterpret_cast<const unsigned int*>(hb + (size_t)csr[j] * D + lane * 2);
        unsigned int u1 = *reinterpret_cast<const unsigned int*>(hb + (size_t)csr[j + 1] * D + lane * 2);
        unsigned int u2 = *reinterpret_cast<const unsigned int*>(hb + (size_t)csr[j + 2] * D + lane * 2);
        unsigned int u3 = *reinterpret_cast<const unsigned int*>(hb + (size_t)csr[j + 3] * D + lane * 2);
        unsigned int u4 = *reinterpret_cast<const unsigned int*>(hb + (size_t)csr[j + 4] * D + lane * 2);
        unsigned int u5 = *reinterpret_cast<const unsigned int*>(hb + (size_t)csr[j + 5] * D + lane * 2);
        unsigned int u6 = *reinterpret_cast<const unsigned int*>(hb + (size_t)csr[j + 6] * D + lane * 2);
        unsigned int u7 = *reinterpret_cast<const unsigned int*>(hb + (size_t)csr[j + 7] * D + lane * 2);
        ax += __uint_as_float(u0 << 16) + __uint_as_float(u1 << 16) +
              __uint_as_float(u2 << 16) + __uint_as_float(u3 << 16) +
              __uint_as_float(u4 << 16) + __uint_as_float(u5 << 16) +
              __uint_as_float(u6 << 16) + __uint_as_float(u7 << 16);
        ay += __uint_as_float(u0 & 0xffff0000u) + __uint_as_float(u1 & 0xffff0000u) +
              __uint_as_float(u2 & 0xffff0000u) + __uint_as_float(u3 & 0xffff0000u) +
              __uint_as_float(u4 & 0xffff0000u) + __uint_as_float(u5 & 0xffff0000u) +
              __uint_as_float(u6 & 0xffff0000u) + __uint_as_float(u7 & 0xffff0000u);
    }
    for (; j < end; ++j) {
        unsigned int u = *reinterpret_cast<const unsigned int*>(hb + (size_t)csr[j] * D + lane * 2);
        ax += __uint_as_float(u << 16);
        ay += __uint_as_float(u & 0xffff0000u);
    }
    int c = end - beg;
    if (c < 1) c = 1;
    float fc = (float)c;
    float2 o;
    o.x = ax / fc;
    o.y = ay / fc;
    *reinterpret_cast<float2*>(agg + (size_t)gw * D + lane * 2) = o;
}

// ---------- fp32-gather fallback aggregate (if workspace too small for shadows) ----------
__global__ __launch_bounds__(256) void aggregate_kernel(const float* __restrict__ h,
                                                        const int* __restrict__ off,
                                                        const int* __restrict__ csr,
                                                        float* __restrict__ agg) {
    int gw = blockIdx.x * 4 + (threadIdx.x >> 6);
    int lane = threadIdx.x & 63;
    if (gw >= N_NODES) return;
    int beg = off[gw], end = off[gw + 1];
    float ax = 0.f, ay = 0.f;
    int j = beg;
    for (; j + 3 < end; j += 4) {
        float2 v0 = *reinterpret_cast<const float2*>(h + (size_t)csr[j] * D + lane * 2);
        float2 v1 = *reinterpret_cast<const float2*>(h + (size_t)csr[j + 1] * D + lane * 2);
        float2 v2 = *reinterpret_cast<const float2*>(h + (size_t)csr[j + 2] * D + lane * 2);
        float2 v3 = *reinterpret_cast<const float2*>(h + (size_t)csr[j + 3] * D + lane * 2);
        ax += v0.x + v1.x + v2.x + v3.x;
        ay += v0.y + v1.y + v2.y + v3.y;
    }
    for (; j < end; ++j) {
        float2 v = *reinterpret_cast<const float2*>(h + (size_t)csr[j] * D + lane * 2);
        ax += v.x;
        ay += v.y;
    }
    int c = end - beg;
    if (c < 1) c = 1;
    float fc = (float)c;
    float2 o;
    o.x = ax / fc;
    o.y = ay / fc;
    *reinterpret_cast<float2*>(agg + (size_t)gw * D + lane * 2) = o;
}

// ---------- dual GEMM: out = A1 @ W1^T + A2 @ W2^T + b (optional relu) ----------
// Optional: outb = bf16 shadow of out (feeds next layer's gather).
// Optional: dec[i][0..1] = out_row_i @ Wo^T + bo (decoder fused, layer 3).
// MFMA 16x16x32 bf16: A row=lane&15, k=8*(lane>>4)+i; B col=lane&15 same k;
// D col=lane&15, row=4*(lane>>4)+r (m89-verified). fp32 accuracy via split hi/lo bf16.
__global__ __launch_bounds__(256) void gemm_kernel(const float* __restrict__ A1,
                                                   const float* __restrict__ A2,
                                                   const float* __restrict__ W1,
                                                   const float* __restrict__ W2,
                                                   const float* __restrict__ bias,
                                                   float* __restrict__ out,
                                                   unsigned short* __restrict__ outb,
                                                   int do_relu,
                                                   const float* __restrict__ Wo,
                                                   const float* __restrict__ bo,
                                                   float* __restrict__ dec) {
    __shared__ float part[4][16][2];
    const int lane = threadIdx.x & 63;
    const int wid = threadIdx.x >> 6;   // 4 waves: col ranges of 32
    const int colbase = wid * 32;
    const int lr = lane & 15;
    const int lg = lane >> 4;

    bf16pair B1[2][4], B2[2][4];
    for (int ct = 0; ct < 2; ++ct) {
        int j = colbase + ct * 16 + lr;
        for (int kk = 0; kk < 4; ++kk) {
            int k = kk * 32 + lg * 8;
            B1[ct][kk] = split8(W1 + j * D + k);
            B2[ct][kk] = split8(W2 + j * D + k);
        }
    }
    float bb0 = bias[colbase + lr];
    float bb1 = bias[colbase + 16 + lr];
    const int decode = (dec != nullptr);
    const int shadow = (outb != nullptr);
    float wo00 = 0.f, wo01 = 0.f, wo10 = 0.f, wo11 = 0.f, bo0 = 0.f, bo1 = 0.f;
    if (decode) {
        wo00 = Wo[colbase + lr];       wo01 = Wo[colbase + 16 + lr];
        wo10 = Wo[D + colbase + lr];   wo11 = Wo[D + colbase + 16 + lr];
        bo0 = bo[0];                   bo1 = bo[1];
    }

    for (int rt = blockIdx.x; rt < NTILES; rt += gridDim.x) {
        int row = rt * 16 + lr;
        bf16pair Af1[4], Af2[4];
        for (int kk = 0; kk < 4; ++kk) {
            int k = kk * 32 + lg * 8;
            Af1[kk] = split8(A1 + (size_t)row * D + k);
            Af2[kk] = split8(A2 + (size_t)row * D + k);
        }
        float p0[4] = {0.f, 0.f, 0.f, 0.f}, p1[4] = {0.f, 0.f, 0.f, 0.f};
        for (int ct = 0; ct < 2; ++ct) {
            float bb = ct ? bb1 : bb0;
            f32x4 acc = {bb, bb, bb, bb};
            for (int kk = 0; kk < 4; ++kk) {
                acc = __builtin_amdgcn_mfma_f32_16x16x32_bf16(Af1[kk].hi, B1[ct][kk].hi, acc, 0, 0, 0);
                acc = __builtin_amdgcn_mfma_f32_16x16x32_bf16(Af1[kk].lo, B1[ct][kk].hi, acc, 0, 0, 0);
                acc = __builtin_amdgcn_mfma_f32_16x16x32_bf16(Af1[kk].hi, B1[ct][kk].lo, acc, 0, 0, 0);
                acc = __builtin_amdgcn_mfma_f32_16x16x32_bf16(Af2[kk].hi, B2[ct][kk].hi, acc, 0, 0, 0);
                acc = __builtin_amdgcn_mfma_f32_16x16x32_bf16(Af2[kk].lo, B2[ct][kk].hi, acc, 0, 0, 0);
                acc = __builtin_amdgcn_mfma_f32_16x16x32_bf16(Af2[kk].hi, B2[ct][kk].lo, acc, 0, 0, 0);
            }
            float woa = ct ? wo01 : wo00;
            float wob = ct ? wo11 : wo10;
            int col = colbase + ct * 16 + lr;
            for (int r = 0; r < 4; ++r) {
                float v = acc[r];
                if (do_relu) v = fmaxf(v, 0.0f);
                size_t idx = (size_t)(rt * 16 + lg * 4 + r) * D + col;
                out[idx] = v;
                if (shadow) outb[idx] = f2bf(v);
                p0[r] += v * woa;
                p1[r] += v * wob;
            }
        }
        if (decode) {
            __syncthreads();   // prior iteration's part-readers done
#pragma unroll
            for (int m = 1; m < 16; m <<= 1) {
#pragma unroll
                for (int r = 0; r < 4; ++r) {
                    p0[r] += __shfl_xor(p0[r], m, 64);
                    p1[r] += __shfl_xor(p1[r], m, 64);
                }
            }
            if (lr == 0) {
#pragma unroll
                for (int r = 0; r < 4; ++r) {
                    part[wid][lg * 4 + r][0] = p0[r];
                    part[wid][lg * 4 + r][1] = p1[r];
                }
            }
            __syncthreads();   // partials ready
            if (wid == 0 && lane < 16) {
                float s0 = part[0][lane][0] + part[1][lane][0] + part[2][lane][0] + part[3][lane][0] + bo0;
                float s1 = part[0][lane][1] + part[1][lane][1] + part[2][lane][1] + part[3][lane][1] + bo1;
                float2 o;
                o.x = s0;
                o.y = s1;
                *reinterpret_cast<float2*>(dec + (size_t)(rt * 16 + lane) * 2) = o;
            }
        }
    }
}

extern "C" void kernel_launch(void* const* d_in, const int* in_sizes, int n_in,
                              void* d_out, int out_size, void* d_ws, size_t ws_size,
                              hipStream_t stream) {
    const float* x   = (const float*)d_in[0];
    const int* ew    = (const int*)d_in[1];
    const float* Wl1 = (const float*)d_in[2];
    const float* Wr1 = (const float*)d_in[3];
    const float* b1  = (const float*)d_in[4];
    const float* Wl2 = (const float*)d_in[5];
    const float* Wr2 = (const float*)d_in[6];
    const float* b2  = (const float*)d_in[7];
    const float* Wl3 = (const float*)d_in[8];
    const float* Wr3 = (const float*)d_in[9];
    const float* b3  = (const float*)d_in[10];
    const float* Wo  = (const float*)d_in[11];
    const float* bo  = (const float*)d_in[12];

    char* ws = (char*)d_ws;
    size_t o = 0;
    auto alloc = [&](size_t bytes) {
        char* p = ws + o;
        o += (bytes + 255) & ~(size_t)255;
        return p;
    };
    int* flag   = (int*)alloc(4);
    int* cnt    = (int*)alloc((size_t)N_NODES * 4);
    int* off    = (int*)alloc((size_t)(N_NODES + 1) * 4);
    int* cursor = (int*)alloc((size_t)N_NODES * 4);
    int* csr    = (int*)alloc((size_t)N_EDGES * 4);
    int* bsum   = (int*)alloc((size_t)NB * 4);
    int* bbase  = (int*)alloc((size_t)NB * 4);
    float* agg  = (float*)alloc((size_t)N_NODES * D * 4);
    float* h1   = (float*)alloc((size_t)N_NODES * D * 4);
    float* h2   = (float*)alloc((size_t)N_NODES * D * 4);
    size_t base_end = o;
    // bf16 shadows: xb aliases h2b (xb dead after agg1; h2b born at gemm2)
    unsigned short* xb_h2b = (unsigned short*)alloc((size_t)N_NODES * D * 2);
    unsigned short* h1b    = (unsigned short*)alloc((size_t)N_NODES * D * 2);
    const bool use_bf16 = (o <= ws_size);
    (void)base_end;

    float* outp = (float*)d_out;                 // [N,2]
    float* h3   = outp + (size_t)N_NODES * 2;    // [N,128], tail of d_out

    hipMemsetAsync(cnt, 0, (size_t)N_NODES * 4, stream);
    detect_kernel<<<1, 256, 0, stream>>>(ew, flag);
    count_kernel<<<(N_EDGES + 255) / 256, 256, 0, stream>>>(ew, flag, cnt);
    scan1_kernel<<<NB, 256, 0, stream>>>(cnt, off, bsum);
    scan2_kernel<<<1, 256, 0, stream>>>(bsum, bbase, off);
    scan3_kernel<<<NB, 256, 0, stream>>>(off, bbase, cursor);
    fill_kernel<<<(N_EDGES + 255) / 256, 256, 0, stream>>>(ew, flag, cursor, csr);

    const int AGG_BLOCKS = (N_NODES + 3) / 4;   // 12500: one wave per node

    if (use_bf16) {
        tobf16_kernel<<<3125, 256, 0, stream>>>(x, xb_h2b);   // 6.4M elts exactly
        aggregate_bf16_kernel<<<AGG_BLOCKS, 256, 0, stream>>>(xb_h2b, off, csr, agg);
        gemm_kernel<<<512, 256, 0, stream>>>(agg, x, Wl1, Wr1, b1, h1, h1b, 1,
                                             nullptr, nullptr, nullptr);
        aggregate_bf16_kernel<<<AGG_BLOCKS, 256, 0, stream>>>(h1b, off, csr, agg);
        gemm_kernel<<<512, 256, 0, stream>>>(agg, h1, Wl2, Wr2, b2, h2, xb_h2b, 1,
                                             nullptr, nullptr, nullptr);
        aggregate_bf16_kernel<<<AGG_BLOCKS, 256, 0, stream>>>(xb_h2b, off, csr, agg);
        gemm_kernel<<<512, 256, 0, stream>>>(agg, h2, Wl3, Wr3, b3, h3, nullptr, 0,
                                             Wo, bo, outp);
    } else {
        aggregate_kernel<<<AGG_BLOCKS, 256, 0, stream>>>(x, off, csr, agg);
        gemm_kernel<<<512, 256, 0, stream>>>(agg, x, Wl1, Wr1, b1, h1, nullptr, 1,
                                             nullptr, nullptr, nullptr);
        aggregate_kernel<<<AGG_BLOCKS, 256, 0, stream>>>(h1, off, csr, agg);
        gemm_kernel<<<512, 256, 0, stream>>>(agg, h1, Wl2, Wr2, b2, h2, nullptr, 1,
                                             nullptr, nullptr, nullptr);
        aggregate_kernel<<<AGG_BLOCKS, 256, 0, stream>>>(h2, off, csr, agg);
        gemm_kernel<<<512, 256, 0, stream>>>(agg, h2, Wl3, Wr3, b3, h3, nullptr, 0,
                                             Wo, bo, outp);
    }
}

// Round 14
// 402.584 us; speedup vs baseline: 1.8036x; 1.0727x over previous
//
#include <hip/hip_runtime.h>

// GraphSAGE on MI355X — split aggregate/GEMM, bf16-resident hidden states,
// decoder fused into layer-3 GEMM, hierarchical scan.
// R13: fused agg+gemm reverted (grid-shape conflict). R14: nt-store reverted
// (WRITE_SIZE 52->64 MB regression); h1/h2 stored bf16-ONLY (fp32 h dropped);
// A2 self-operand reads bf16 hi (layers 2/3), x fp32 full-split (layer 1).

#define N_NODES 50000
#define N_EDGES 800000
#define D 128
#define NB ((N_NODES + 255) / 256)   // 196 scan blocks
#define NTILES (N_NODES / 16)        // 3125 row tiles

typedef __bf16 bf16x8 __attribute__((ext_vector_type(8)));
typedef float f32x4 __attribute__((ext_vector_type(4)));
typedef unsigned short u16x8 __attribute__((ext_vector_type(8)));

struct bf16pair { bf16x8 hi, lo; };

__device__ inline unsigned short f2bf(float f) {
    unsigned int u = __float_as_uint(f);
    unsigned int r = u + 0x7fffu + ((u >> 16) & 1u);   // RNE
    return (unsigned short)(r >> 16);
}

__device__ inline bf16pair split8(const float* __restrict__ p) {
    f32x4 a = *reinterpret_cast<const f32x4*>(p);
    f32x4 b = *reinterpret_cast<const f32x4*>(p + 4);
    bf16pair r;
#pragma unroll
    for (int i = 0; i < 4; ++i) {
        float v = a[i];
        __bf16 h = (__bf16)v;
        r.hi[i] = h;
        r.lo[i] = (__bf16)(v - (float)h);
    }
#pragma unroll
    for (int i = 0; i < 4; ++i) {
        float v = b[i];
        __bf16 h = (__bf16)v;
        r.hi[4 + i] = h;
        r.lo[4 + i] = (__bf16)(v - (float)h);
    }
    return r;
}

// ---------- edge dtype detect ----------
__global__ void detect_kernel(const int* __restrict__ ew, int* __restrict__ flag) {
    __shared__ int s;
    if (threadIdx.x == 0) s = 0;
    __syncthreads();
    int v = 0;
    for (int i = threadIdx.x; i < 1024; i += 256) v |= ew[2 * i + 1];
    if (v) atomicOr(&s, 1);
    __syncthreads();
    if (threadIdx.x == 0) flag[0] = s ? 1 : 2;   // words per element
}

// ---------- CSR build ----------
__global__ void count_kernel(const int* __restrict__ ew, const int* __restrict__ flag,
                             int* __restrict__ cnt) {
    int st = flag[0];
    int e = blockIdx.x * blockDim.x + threadIdx.x;
    if (e < N_EDGES) {
        int d = ew[(size_t)st * (N_EDGES + e)];
        atomicAdd(&cnt[d], 1);
    }
}

__global__ __launch_bounds__(256) void scan1_kernel(const int* __restrict__ cnt,
                                                    int* __restrict__ off,
                                                    int* __restrict__ bsum) {
    const int tid = threadIdx.x, lane = tid & 63, wid = tid >> 6;
    const int i = blockIdx.x * 256 + tid;
    int orig = (i < N_NODES) ? cnt[i] : 0;
    int v = orig;
#pragma unroll
    for (int d = 1; d < 64; d <<= 1) {
        int t = __shfl_up(v, d, 64);
        if (lane >= d) v += t;
    }
    __shared__ int ws[4];
    if (lane == 63) ws[wid] = v;
    __syncthreads();
    int base = 0;
    for (int w = 0; w < wid; ++w) base += ws[w];
    v += base;
    if (i < N_NODES) off[i] = v - orig;
    if (tid == 255) bsum[blockIdx.x] = v;
}

__global__ __launch_bounds__(256) void scan2_kernel(const int* __restrict__ bsum,
                                                    int* __restrict__ bbase,
                                                    int* __restrict__ off) {
    const int tid = threadIdx.x, lane = tid & 63, wid = tid >> 6;
    int orig = (tid < NB) ? bsum[tid] : 0;
    int v = orig;
#pragma unroll
    for (int d = 1; d < 64; d <<= 1) {
        int t = __shfl_up(v, d, 64);
        if (lane >= d) v += t;
    }
    __shared__ int ws[4];
    if (lane == 63) ws[wid] = v;
    __syncthreads();
    int base = 0;
    for (int w = 0; w < wid; ++w) base += ws[w];
    v += base;
    if (tid < NB) bbase[tid] = v - orig;
    if (tid == NB - 1) off[N_NODES] = v;
}

__global__ __launch_bounds__(256) void scan3_kernel(int* __restrict__ off,
                                                    const int* __restrict__ bbase,
                                                    int* __restrict__ cursor) {
    int i = blockIdx.x * 256 + threadIdx.x;
    if (i < N_NODES) {
        int v = off[i] + bbase[blockIdx.x];
        off[i] = v;
        cursor[i] = v;
    }
}

__global__ void fill_kernel(const int* __restrict__ ew, const int* __restrict__ flag,
                            int* __restrict__ cursor, int* __restrict__ csr) {
    int st = flag[0];
    int e = blockIdx.x * blockDim.x + threadIdx.x;
    if (e < N_EDGES) {
        int d = ew[(size_t)st * (N_EDGES + e)];
        int sidx = ew[(size_t)st * e];
        int pos = atomicAdd(&cursor[d], 1);
        csr[pos] = sidx;   // R14: plain store (nt-store raised WRITE_SIZE 52->64 MB)
    }
}

// ---------- fp32 -> bf16 convert for x ----------
__global__ __launch_bounds__(256) void tobf16_kernel(const float* __restrict__ in,
                                                     unsigned short* __restrict__ out) {
    int i = blockIdx.x * 256 + threadIdx.x;   // 800000 threads x 8 elts = 6.4M
    const float* p = in + (size_t)i * 8;
    f32x4 a = *reinterpret_cast<const f32x4*>(p);
    f32x4 b = *reinterpret_cast<const f32x4*>(p + 4);
    u16x8 r;
#pragma unroll
    for (int k = 0; k < 4; ++k) r[k] = f2bf(a[k]);
#pragma unroll
    for (int k = 0; k < 4; ++k) r[4 + k] = f2bf(b[k]);
    *reinterpret_cast<u16x8*>(out + (size_t)i * 8) = r;
}

// ---------- segment-mean aggregation over bf16 rows: one wave per node ----------
__global__ __launch_bounds__(256) void aggregate_bf16_kernel(const unsigned short* __restrict__ hb,
                                                             const int* __restrict__ off,
                                                             const int* __restrict__ csr,
                                                             float* __restrict__ agg) {
    int gw = blockIdx.x * 4 + (threadIdx.x >> 6);
    int lane = threadIdx.x & 63;
    if (gw >= N_NODES) return;
    int beg = off[gw], end = off[gw + 1];
    float ax = 0.f, ay = 0.f;
    int j = beg;
    for (; j + 7 < end; j += 8) {
        unsigned int u0 = *reinterpret_cast<const unsigned int*>(hb + (size_t)csr[j] * D + lane * 2);
        unsigned int u1 = *reinterpret_cast<const unsigned int*>(hb + (size_t)csr[j + 1] * D + lane * 2);
        unsigned int u2 = *reinterpret_cast<const unsigned int*>(hb + (size_t)csr[j + 2] * D + lane * 2);
        unsigned int u3 = *reinterpret_cast<const unsigned int*>(hb + (size_t)csr[j + 3] * D + lane * 2);
        unsigned int u4 = *reinterpret_cast<const unsigned int*>(hb + (size_t)csr[j + 4] * D + lane * 2);
        unsigned int u5 = *reinterpret_cast<const unsigned int*>(hb + (size_t)csr[j + 5] * D + lane * 2);
        unsigned int u6 = *reinterpret_cast<const unsigned int*>(hb + (size_t)csr[j + 6] * D + lane * 2);
        unsigned int u7 = *reinterpret_cast<const unsigned int*>(hb + (size_t)csr[j + 7] * D + lane * 2);
        ax += __uint_as_float(u0 << 16) + __uint_as_float(u1 << 16) +
              __uint_as_float(u2 << 16) + __uint_as_float(u3 << 16) +
              __uint_as_float(u4 << 16) + __uint_as_float(u5 << 16) +
              __uint_as_float(u6 << 16) + __uint_as_float(u7 << 16);
        ay += __uint_as_float(u0 & 0xffff0000u) + __uint_as_float(u1 & 0xffff0000u) +
              __uint_as_float(u2 & 0xffff0000u) + __uint_as_float(u3 & 0xffff0000u) +
              __uint_as_float(u4 & 0xffff0000u) + __uint_as_float(u5 & 0xffff0000u) +
              __uint_as_float(u6 & 0xffff0000u) + __uint_as_float(u7 & 0xffff0000u);
    }
    for (; j < end; ++j) {
        unsigned int u = *reinterpret_cast<const unsigned int*>(hb + (size_t)csr[j] * D + lane * 2);
        ax += __uint_as_float(u << 16);
        ay += __uint_as_float(u & 0xffff0000u);
    }
    int c = end - beg;
    if (c < 1) c = 1;
    float fc = (float)c;
    float2 o;
    o.x = ax / fc;
    o.y = ay / fc;
    *reinterpret_cast<float2*>(agg + (size_t)gw * D + lane * 2) = o;
}

// ---------- dual GEMM: out = A1 @ W1^T + A2 @ W2^T + b (optional relu) ----------
// A1: fp32 (agg), full split. A2: either fp32 (A2f, full split) or bf16 (A2b, hi-only).
// Outputs: out fp32 (nullable) and/or outb bf16 (nullable).
// Optional decoder: dec[i][0..1] = out_row_i @ Wo^T + bo.
// MFMA 16x16x32 bf16: A row=lane&15, k=8*(lane>>4)+i; B col=lane&15 same k;
// D col=lane&15, row=4*(lane>>4)+r (m89-verified).
__global__ __launch_bounds__(256) void gemm_kernel(const float* __restrict__ A1,
                                                   const float* __restrict__ A2f,
                                                   const unsigned short* __restrict__ A2b,
                                                   const float* __restrict__ W1,
                                                   const float* __restrict__ W2,
                                                   const float* __restrict__ bias,
                                                   float* __restrict__ out,
                                                   unsigned short* __restrict__ outb,
                                                   int do_relu,
                                                   const float* __restrict__ Wo,
                                                   const float* __restrict__ bo,
                                                   float* __restrict__ dec) {
    __shared__ float part[4][16][2];
    const int lane = threadIdx.x & 63;
    const int wid = threadIdx.x >> 6;   // 4 waves: col ranges of 32
    const int colbase = wid * 32;
    const int lr = lane & 15;
    const int lg = lane >> 4;

    bf16pair B1[2][4], B2[2][4];
    for (int ct = 0; ct < 2; ++ct) {
        int j = colbase + ct * 16 + lr;
        for (int kk = 0; kk < 4; ++kk) {
            int k = kk * 32 + lg * 8;
            B1[ct][kk] = split8(W1 + j * D + k);
            B2[ct][kk] = split8(W2 + j * D + k);
        }
    }
    float bb0 = bias[colbase + lr];
    float bb1 = bias[colbase + 16 + lr];
    const int decode = (dec != nullptr);
    const int has_out = (out != nullptr);
    const int has_outb = (outb != nullptr);
    const int a2_fp32 = (A2f != nullptr);
    float wo00 = 0.f, wo01 = 0.f, wo10 = 0.f, wo11 = 0.f, bo0 = 0.f, bo1 = 0.f;
    if (decode) {
        wo00 = Wo[colbase + lr];       wo01 = Wo[colbase + 16 + lr];
        wo10 = Wo[D + colbase + lr];   wo11 = Wo[D + colbase + 16 + lr];
        bo0 = bo[0];                   bo1 = bo[1];
    }

    for (int rt = blockIdx.x; rt < NTILES; rt += gridDim.x) {
        int row = rt * 16 + lr;
        bf16pair Af1[4];
        bf16x8 Af2h[4];
        bf16x8 Af2l[4];
        for (int kk = 0; kk < 4; ++kk) {
            int k = kk * 32 + lg * 8;
            Af1[kk] = split8(A1 + (size_t)row * D + k);
            if (a2_fp32) {
                bf16pair p2 = split8(A2f + (size_t)row * D + k);
                Af2h[kk] = p2.hi;
                Af2l[kk] = p2.lo;
            } else {
                Af2h[kk] = *reinterpret_cast<const bf16x8*>(A2b + (size_t)row * D + k);
            }
        }
        float p0[4] = {0.f, 0.f, 0.f, 0.f}, p1[4] = {0.f, 0.f, 0.f, 0.f};
        for (int ct = 0; ct < 2; ++ct) {
            float bb = ct ? bb1 : bb0;
            f32x4 acc = {bb, bb, bb, bb};
            for (int kk = 0; kk < 4; ++kk) {
                acc = __builtin_amdgcn_mfma_f32_16x16x32_bf16(Af1[kk].hi, B1[ct][kk].hi, acc, 0, 0, 0);
                acc = __builtin_amdgcn_mfma_f32_16x16x32_bf16(Af1[kk].lo, B1[ct][kk].hi, acc, 0, 0, 0);
                acc = __builtin_amdgcn_mfma_f32_16x16x32_bf16(Af1[kk].hi, B1[ct][kk].lo, acc, 0, 0, 0);
                acc = __builtin_amdgcn_mfma_f32_16x16x32_bf16(Af2h[kk], B2[ct][kk].hi, acc, 0, 0, 0);
                if (a2_fp32)
                    acc = __builtin_amdgcn_mfma_f32_16x16x32_bf16(Af2l[kk], B2[ct][kk].hi, acc, 0, 0, 0);
                acc = __builtin_amdgcn_mfma_f32_16x16x32_bf16(Af2h[kk], B2[ct][kk].lo, acc, 0, 0, 0);
            }
            float woa = ct ? wo01 : wo00;
            float wob = ct ? wo11 : wo10;
            int col = colbase + ct * 16 + lr;
            for (int r = 0; r < 4; ++r) {
                float v = acc[r];
                if (do_relu) v = fmaxf(v, 0.0f);
                size_t idx = (size_t)(rt * 16 + lg * 4 + r) * D + col;
                if (has_out) out[idx] = v;
                if (has_outb) outb[idx] = f2bf(v);
                p0[r] += v * woa;
                p1[r] += v * wob;
            }
        }
        if (decode) {
            __syncthreads();   // prior iteration's part-readers done
#pragma unroll
            for (int m = 1; m < 16; m <<= 1) {
#pragma unroll
                for (int r = 0; r < 4; ++r) {
                    p0[r] += __shfl_xor(p0[r], m, 64);
                    p1[r] += __shfl_xor(p1[r], m, 64);
                }
            }
            if (lr == 0) {
#pragma unroll
                for (int r = 0; r < 4; ++r) {
                    part[wid][lg * 4 + r][0] = p0[r];
                    part[wid][lg * 4 + r][1] = p1[r];
                }
            }
            __syncthreads();   // partials ready
            if (wid == 0 && lane < 16) {
                float s0 = part[0][lane][0] + part[1][lane][0] + part[2][lane][0] + part[3][lane][0] + bo0;
                float s1 = part[0][lane][1] + part[1][lane][1] + part[2][lane][1] + part[3][lane][1] + bo1;
                float2 o;
                o.x = s0;
                o.y = s1;
                *reinterpret_cast<float2*>(dec + (size_t)(rt * 16 + lane) * 2) = o;
            }
        }
    }
}

extern "C" void kernel_launch(void* const* d_in, const int* in_sizes, int n_in,
                              void* d_out, int out_size, void* d_ws, size_t ws_size,
                              hipStream_t stream) {
    const float* x   = (const float*)d_in[0];
    const int* ew    = (const int*)d_in[1];
    const float* Wl1 = (const float*)d_in[2];
    const float* Wr1 = (const float*)d_in[3];
    const float* b1  = (const float*)d_in[4];
    const float* Wl2 = (const float*)d_in[5];
    const float* Wr2 = (const float*)d_in[6];
    const float* b2  = (const float*)d_in[7];
    const float* Wl3 = (const float*)d_in[8];
    const float* Wr3 = (const float*)d_in[9];
    const float* b3  = (const float*)d_in[10];
    const float* Wo  = (const float*)d_in[11];
    const float* bo  = (const float*)d_in[12];

    char* ws = (char*)d_ws;
    size_t o = 0;
    auto alloc = [&](size_t bytes) {
        char* p = ws + o;
        o += (bytes + 255) & ~(size_t)255;
        return p;
    };
    int* flag   = (int*)alloc(4);
    int* cnt    = (int*)alloc((size_t)N_NODES * 4);
    int* off    = (int*)alloc((size_t)(N_NODES + 1) * 4);
    int* cursor = (int*)alloc((size_t)N_NODES * 4);
    int* csr    = (int*)alloc((size_t)N_EDGES * 4);
    int* bsum   = (int*)alloc((size_t)NB * 4);
    int* bbase  = (int*)alloc((size_t)NB * 4);
    float* agg  = (float*)alloc((size_t)N_NODES * D * 4);           // 25.6 MB
    unsigned short* xb  = (unsigned short*)alloc((size_t)N_NODES * D * 2);  // 12.8 MB
    unsigned short* h1b = (unsigned short*)alloc((size_t)N_NODES * D * 2);
    unsigned short* h2b = (unsigned short*)alloc((size_t)N_NODES * D * 2);
    // total ~67.5 MB — under the ~107 MB proven available in R3/R4.

    float* outp = (float*)d_out;                 // [N,2]
    float* h3   = outp + (size_t)N_NODES * 2;    // [N,128], tail of d_out

    hipMemsetAsync(cnt, 0, (size_t)N_NODES * 4, stream);
    detect_kernel<<<1, 256, 0, stream>>>(ew, flag);
    count_kernel<<<(N_EDGES + 255) / 256, 256, 0, stream>>>(ew, flag, cnt);
    scan1_kernel<<<NB, 256, 0, stream>>>(cnt, off, bsum);
    scan2_kernel<<<1, 256, 0, stream>>>(bsum, bbase, off);
    scan3_kernel<<<NB, 256, 0, stream>>>(off, bbase, cursor);
    fill_kernel<<<(N_EDGES + 255) / 256, 256, 0, stream>>>(ew, flag, cursor, csr);

    const int AGG_BLOCKS = (N_NODES + 3) / 4;   // 12500: one wave per node

    tobf16_kernel<<<3125, 256, 0, stream>>>(x, xb);   // 6.4M elts exactly

    aggregate_bf16_kernel<<<AGG_BLOCKS, 256, 0, stream>>>(xb, off, csr, agg);
    gemm_kernel<<<512, 256, 0, stream>>>(agg, x, nullptr, Wl1, Wr1, b1,
                                         nullptr, h1b, 1, nullptr, nullptr, nullptr);

    aggregate_bf16_kernel<<<AGG_BLOCKS, 256, 0, stream>>>(h1b, off, csr, agg);
    gemm_kernel<<<512, 256, 0, stream>>>(agg, nullptr, h1b, Wl2, Wr2, b2,
                                         nullptr, h2b, 1, nullptr, nullptr, nullptr);

    aggregate_bf16_kernel<<<AGG_BLOCKS, 256, 0, stream>>>(h2b, off, csr, agg);
    gemm_kernel<<<512, 256, 0, stream>>>(agg, nullptr, h2b, Wl3, Wr3, b3,
                                         h3, nullptr, 0, Wo, bo, outp);
}